// Round 6
// baseline (51.646 us; speedup 1.0000x reference)
//
#include <hip/hip_runtime.h>
#include <hip/hip_bf16.h>

typedef __bf16 v8bf __attribute__((ext_vector_type(8)));
typedef float f32x16 __attribute__((ext_vector_type(16)));
typedef unsigned int uint;
typedef unsigned short ushort;

#define GLOAD16(gsrc, ldst)                                                       \
  __builtin_amdgcn_global_load_lds(                                               \
      (const __attribute__((address_space(1))) unsigned int*)(gsrc),              \
      (__attribute__((address_space(3))) unsigned int*)(ldst), 16, 0, 0)

__device__ inline f32x16 zero16() {
  f32x16 z;
#pragma unroll
  for (int i = 0; i < 16; i++) z[i] = 0.f;
  return z;
}

__device__ inline uint pack_bf16(float a, float b) {
  union { __bf16 h[2]; uint u; } c;
  c.h[0] = (__bf16)a;
  c.h[1] = (__bf16)b;
  return c.u;
}

// ---------------------------------------------------------------------------
// Kernel 0: Wt_s = transpose of [Wq|Wk|Wv] -> bf16, PRE-SWIZZLED:
// element (n,k) at byte n*2048 + (k>>6)*128 + (((k&63)*2) ^ ((n&7)<<4)).
// ---------------------------------------------------------------------------
__global__ void prep_wt(const float* __restrict__ Wq, const float* __restrict__ Wk,
                        const float* __restrict__ Wv, char* __restrict__ Wt_s) {
  __shared__ __bf16 tile[64][74];
  const int mat = blockIdx.x >> 4;
  const int c0 = (blockIdx.x & 15) * 64;
  const float* src = (mat == 0) ? Wq : (mat == 1) ? Wk : Wv;
  const int t = threadIdx.x;  // 256 threads
  {
    const int r = t >> 2;
    const int ch = (t & 3) * 16;
    const float4* s4 = (const float4*)(src + (size_t)(c0 + r) * 64 + ch);
#pragma unroll
    for (int j = 0; j < 4; j++) {
      float4 f = s4[j];
      tile[r][ch + 4 * j + 0] = (__bf16)f.x;
      tile[r][ch + 4 * j + 1] = (__bf16)f.y;
      tile[r][ch + 4 * j + 2] = (__bf16)f.z;
      tile[r][ch + 4 * j + 3] = (__bf16)f.w;
    }
  }
  __syncthreads();
  const int h = t >> 2;
  const int cc = (t & 3) * 16;
  union { __bf16 o[16]; uint4 u[2]; } pk;
#pragma unroll
  for (int j = 0; j < 16; j++) pk.o[j] = tile[cc + j][h];
  const int n = mat * 64 + h;
  char* base = Wt_s + (size_t)n * 2048 + (c0 >> 6) * 128;
  const int bc = cc * 2;
  *(uint4*)(base + ((bc) ^ ((n & 7) << 4))) = pk.u[0];
  *(uint4*)(base + ((bc + 16) ^ ((n & 7) << 4))) = pk.u[1];
}

// ---------------------------------------------------------------------------
// Kernel 1: KQV[32768][192] = x * W. 512 blocks x 256 threads, 2 blocks/CU
// (LDS 80 KB exactly). Block tile 64x192; wave tile 32x96; BK=64.
// A staged as RAW FP32 via global_load_lds (pre-swizzled per-lane source,
// linear LDS dest); bf16 conversion happens at ds_read time. W staged via
// global_load_lds from pre-swizzled Wt_s. Clean 2-phase: STAGE(t+1) -> MMA(t)
// -> one barrier. No register-held load data -> no mid-step vmcnt stalls.
// ---------------------------------------------------------------------------
__launch_bounds__(256, 2)
__global__ void proj_kernel(const float* __restrict__ x, const char* __restrict__ Wt_s,
                            __bf16* __restrict__ KQV) {
  __shared__ char lds[81920];
  char* A0 = lds;            // [64 rows][256 B fp32] swizzled, 16 KB
  char* A1 = lds + 16384;
  char* W0 = lds + 32768;    // [192 rows][128 B bf16] swizzled, 24 KB
  char* W1 = lds + 57344;

  const int tid = threadIdx.x;
  const int lane = tid & 63;
  const int wave = tid >> 6;  // 0..3
  const int wm = wave >> 1;
  const int wn = wave & 1;
  const int row0 = blockIdx.x * 64;

  // A staging: linear slot L = wave*64 + i*256 + lane; row r = L>>4, slot s = L&15.
  // LDS gets slot byte r*256 + s*16; source chunk c4 = s ^ (r&15)  (involution).
  const int sL = wave * 64 + lane;
  const int sr = sL >> 4;        // +4 rows per i (i*16)
  const int ss = sL & 15;

  f32x16 acc[3];
#pragma unroll
  for (int i = 0; i < 3; i++) acc[i] = zero16();

#define GA(t, Abuf)                                                               \
  {                                                                               \
    _Pragma("unroll") for (int i = 0; i < 4; i++) {                               \
      int r = sr + i * 16;                                                        \
      int c4 = ss ^ (r & 15);                                                     \
      GLOAD16(x + (size_t)(row0 + r) * 1024 + (t) * 64 + c4 * 4,                  \
              Abuf + wave * 1024 + i * 4096);                                     \
    }                                                                             \
  }

#define GW(t, Wbuf)                                                               \
  {                                                                               \
    _Pragma("unroll") for (int j = 0; j < 6; j++) {                               \
      int idx = wave * 64 + j * 256 + lane;                                       \
      GLOAD16(Wt_s + (size_t)(idx >> 3) * 2048 + (t) * 128 + (idx & 7) * 16,      \
              Wbuf + wave * 1024 + j * 4096);                                     \
    }                                                                             \
  }

#define MMA(Abuf, Wbuf)                                                           \
  {                                                                               \
    _Pragma("unroll") for (int ks = 0; ks < 4; ks++) {                            \
      int arow = wm * 32 + (lane & 31);                                           \
      int hi = lane >> 5;                                                         \
      int c4 = ks * 4 + hi * 2;                                                   \
      float4 f0 = *(const float4*)(Abuf + arow * 256 +                            \
                                   ((c4 * 16) ^ ((arow & 15) << 4)));             \
      float4 f1 = *(const float4*)(Abuf + arow * 256 +                            \
                                   (((c4 + 1) * 16) ^ ((arow & 15) << 4)));       \
      union { __bf16 h[8]; v8bf v; } av;                                          \
      av.h[0] = (__bf16)f0.x; av.h[1] = (__bf16)f0.y;                             \
      av.h[2] = (__bf16)f0.z; av.h[3] = (__bf16)f0.w;                             \
      av.h[4] = (__bf16)f1.x; av.h[5] = (__bf16)f1.y;                             \
      av.h[6] = (__bf16)f1.z; av.h[7] = (__bf16)f1.w;                             \
      int kb = ks * 32 + (hi << 4);                                               \
      _Pragma("unroll") for (int nf = 0; nf < 3; nf++) {                          \
        int brow = wn * 96 + nf * 32 + (lane & 31);                               \
        v8bf bv = *(const v8bf*)(Wbuf + brow * 128 + (kb ^ ((brow & 7) << 4)));   \
        acc[nf] = __builtin_amdgcn_mfma_f32_32x32x16_bf16(av.v, bv, acc[nf], 0, 0, 0); \
      }                                                                           \
    }                                                                             \
  }

  // prologue
  GA(0, A0);
  GW(0, W0);
  __syncthreads();

  for (int t = 0; t < 16; t += 2) {
    GA(t + 1, A1);
    GW(t + 1, W1);
    MMA(A0, W0);
    __syncthreads();
    if (t + 2 < 16) {
      GA(t + 2, A0);
      GW(t + 2, W0);
    }
    MMA(A1, W1);
    __syncthreads();
  }

  // epilogue: write bf16 KQV (half-wave 64B-contiguous stores)
#pragma unroll
  for (int nf = 0; nf < 3; nf++) {
#pragma unroll
    for (int r = 0; r < 16; r++) {
      int row = row0 + wm * 32 + (r & 3) + ((r >> 2) << 3) + ((lane >> 5) << 2);
      int col = wn * 96 + nf * 32 + (lane & 31);
      KQV[(size_t)row * 192 + col] = (__bf16)acc[nf][r];
    }
  }
#undef GA
#undef GW
#undef MMA
}

// ---------------------------------------------------------------------------
// Kernel 2: causal attention per batch. 256 blocks (= 128 batches x 2 halves)
// x 256 threads (4 waves). Wave owns 32 q-rows. Swapped QK^T -> lane-local softmax.
// (unchanged from R5 — validated)
// ---------------------------------------------------------------------------
__launch_bounds__(256, 1)
__global__ void attn_kernel(const __bf16* __restrict__ KQV, float* __restrict__ out) {
  __shared__ uint4 lds4[81920 / 16];  // K:[256][64] 32KB | Vt:[64][256] 32KB | Q:[128][64] 16KB
  char* Klds = (char*)lds4;
  char* Vlds = (char*)lds4 + 32768;
  char* Qlds = (char*)lds4 + 65536;

  const int tid = threadIdx.x;
  const int lane = tid & 63;
  const int wave = tid >> 6;  // 0..3
  const int b = blockIdx.x >> 1;
  const int half = blockIdx.x & 1;
  const int bt0 = half * 128;
  const size_t base = (size_t)b * 256 * 192;

  {
    int s = tid;
    const uint4* src = (const uint4*)(KQV + base + (size_t)s * 192 + 64);
#pragma unroll
    for (int i = 0; i < 8; i++) {
      uint4 v = src[i];
      int byte = s * 128 + ((i * 16) ^ ((s & 7) << 4));
      *(uint4*)(Klds + byte) = v;
    }
  }
  {
    int s = tid;
    const uint4* src = (const uint4*)(KQV + base + (size_t)s * 192 + 128);
#pragma unroll
    for (int i = 0; i < 8; i++) {
      uint4 v = src[i];
      const ushort* e = (const ushort*)&v;
#pragma unroll
      for (int j = 0; j < 8; j++) {
        int h = i * 8 + j;
        int byte = h * 512 + ((s * 2) ^ ((h & 7) << 4));
        *(ushort*)(Vlds + byte) = e[j];
      }
    }
  }
#pragma unroll
  for (int i = 0; i < 4; i++) {
    int c = tid + i * 256;
    int r = c >> 3, cc = c & 7;
    uint4 v = *(const uint4*)(KQV + base + (size_t)(bt0 + r) * 192 + cc * 8);
    int byte = r * 128 + ((cc * 16) ^ ((r & 7) << 4));
    *(uint4*)(Qlds + byte) = v;
  }
  __syncthreads();

  const int t0 = bt0 + wave * 32;
  const int tg = t0 + (lane & 31);
  const int nf = (t0 >> 5) + 1;

  f32x16 sacc[8];
#pragma unroll
  for (int sf = 0; sf < 8; sf++) {
    f32x16 sv = zero16();
    if (sf < nf) {
#pragma unroll
      for (int ks = 0; ks < 4; ks++) {
        int kbyte = ks * 32 + ((lane >> 5) << 4);
        int krow = sf * 32 + (lane & 31);
        v8bf a = *(const v8bf*)(Klds + krow * 128 + (kbyte ^ ((krow & 7) << 4)));
        int qrow = wave * 32 + (lane & 31);
        v8bf bq = *(const v8bf*)(Qlds + qrow * 128 + (kbyte ^ ((qrow & 7) << 4)));
        sv = __builtin_amdgcn_mfma_f32_32x32x16_bf16(a, bq, sv, 0, 0, 0);
      }
    }
    sacc[sf] = sv;
  }

  float m = -1e30f;
#pragma unroll
  for (int sf = 0; sf < 8; sf++) {
    if (sf < nf) {
#pragma unroll
      for (int r = 0; r < 16; r++) {
        int sg = sf * 32 + (r & 3) + ((r >> 2) << 3) + ((lane >> 5) << 2);
        float v = sacc[sf][r] * 0.125f;
        v = (sg > tg) ? -1e30f : v;
        sacc[sf][r] = v;
        m = fmaxf(m, v);
      }
    }
  }
  m = fmaxf(m, __shfl_xor(m, 32, 64));
  float l = 0.f;
#pragma unroll
  for (int sf = 0; sf < 8; sf++) {
    if (sf < nf) {
#pragma unroll
      for (int r = 0; r < 16; r++) {
        float p = __expf(sacc[sf][r] - m);
        sacc[sf][r] = p;
        l += p;
      }
    }
  }
  l += __shfl_xor(l, 32, 64);
  float inv = 1.0f / l;

  f32x16 oacc[2];
  oacc[0] = zero16();
  oacc[1] = zero16();
  const bool hiLane = (lane >= 32);
#pragma unroll
  for (int sf = 0; sf < 8; sf++) {
    if (sf < nf) {
      uint w[8], ow[8];
#pragma unroll
      for (int q = 0; q < 4; q++) {
        w[2 * q]     = pack_bf16(sacc[sf][4 * q] * inv,     sacc[sf][4 * q + 1] * inv);
        w[2 * q + 1] = pack_bf16(sacc[sf][4 * q + 2] * inv, sacc[sf][4 * q + 3] * inv);
      }
#pragma unroll
      for (int i = 0; i < 8; i++) ow[i] = (uint)__shfl_xor((int)w[i], 32, 64);
#pragma unroll
      for (int ks = 0; ks < 2; ks++) {
        int bse = 4 * ks;
        union { uint u[4]; v8bf v; } A;
        A.u[0] = hiLane ? ow[bse + 2] : w[bse + 0];
        A.u[1] = hiLane ? ow[bse + 3] : w[bse + 1];
        A.u[2] = hiLane ? w[bse + 2] : ow[bse + 0];
        A.u[3] = hiLane ? w[bse + 3] : ow[bse + 1];
        int sbyte0 = (sf * 32 + ks * 16) * 2 + ((lane >> 5) << 4);
#pragma unroll
        for (int hf = 0; hf < 2; hf++) {
          int vrow = hf * 32 + (lane & 31);
          v8bf bv = *(const v8bf*)(Vlds + vrow * 512 + (sbyte0 ^ ((vrow & 7) << 4)));
          oacc[hf] = __builtin_amdgcn_mfma_f32_32x32x16_bf16(A.v, bv, oacc[hf], 0, 0, 0);
        }
      }
    }
  }

#pragma unroll
  for (int hf = 0; hf < 2; hf++) {
#pragma unroll
    for (int r = 0; r < 16; r++) {
      int t = t0 + (r & 3) + ((r >> 2) << 3) + ((lane >> 5) << 2);
      int h = hf * 32 + (lane & 31);
      out[((size_t)b * 256 + t) * 64 + h] = oacc[hf][r];
    }
  }
}

// ---------------------------------------------------------------------------
extern "C" void kernel_launch(void* const* d_in, const int* in_sizes, int n_in,
                              void* d_out, int out_size, void* d_ws, size_t ws_size,
                              hipStream_t stream) {
  const float* x  = (const float*)d_in[0];
  const float* Wk = (const float*)d_in[1];
  const float* Wq = (const float*)d_in[2];
  const float* Wv = (const float*)d_in[3];
  float* out = (float*)d_out;

  // workspace: KQV bf16 [32768][192] (12.58 MB), then pre-swizzled Wt (384 KB)
  __bf16* KQV = (__bf16*)d_ws;
  char* Wt_s  = (char*)d_ws + (size_t)32768 * 192 * 2;

  prep_wt<<<48, 256, 0, stream>>>(Wq, Wk, Wv, Wt_s);
  proj_kernel<<<512, 256, 0, stream>>>(x, Wt_s, KQV);
  attn_kernel<<<256, 256, 0, stream>>>(KQV, out);
}

// Round 7
// 45.672 us; speedup vs baseline: 1.1308x; 1.1308x over previous
//
#include <hip/hip_runtime.h>
#include <hip/hip_bf16.h>

typedef __bf16 v8bf __attribute__((ext_vector_type(8)));
typedef float f32x16 __attribute__((ext_vector_type(16)));
typedef unsigned int uint;
typedef unsigned short ushort;

#define GLOAD16(gsrc, ldst)                                                       \
  __builtin_amdgcn_global_load_lds(                                               \
      (const __attribute__((address_space(1))) unsigned int*)(gsrc),              \
      (__attribute__((address_space(3))) unsigned int*)(ldst), 16, 0, 0)

__device__ inline f32x16 zero16() {
  f32x16 z;
#pragma unroll
  for (int i = 0; i < 16; i++) z[i] = 0.f;
  return z;
}

__device__ inline uint pack_bf16(float a, float b) {
  union { __bf16 h[2]; uint u; } c;
  c.h[0] = (__bf16)a;
  c.h[1] = (__bf16)b;
  return c.u;
}

// ---------------------------------------------------------------------------
// Kernel 0: Wt_s = transpose of [Wq|Wk|Wv] -> bf16, PRE-SWIZZLED:
// element (n,k) at byte n*2048 + (k>>6)*128 + (((k&63)*2) ^ ((n&7)<<4)).
// (unchanged from R5 — validated)
// ---------------------------------------------------------------------------
__global__ void prep_wt(const float* __restrict__ Wq, const float* __restrict__ Wk,
                        const float* __restrict__ Wv, char* __restrict__ Wt_s) {
  __shared__ __bf16 tile[64][74];
  const int mat = blockIdx.x >> 4;
  const int c0 = (blockIdx.x & 15) * 64;
  const float* src = (mat == 0) ? Wq : (mat == 1) ? Wk : Wv;
  const int t = threadIdx.x;  // 256 threads
  {
    const int r = t >> 2;
    const int ch = (t & 3) * 16;
    const float4* s4 = (const float4*)(src + (size_t)(c0 + r) * 64 + ch);
#pragma unroll
    for (int j = 0; j < 4; j++) {
      float4 f = s4[j];
      tile[r][ch + 4 * j + 0] = (__bf16)f.x;
      tile[r][ch + 4 * j + 1] = (__bf16)f.y;
      tile[r][ch + 4 * j + 2] = (__bf16)f.z;
      tile[r][ch + 4 * j + 3] = (__bf16)f.w;
    }
  }
  __syncthreads();
  const int h = t >> 2;
  const int cc = (t & 3) * 16;
  union { __bf16 o[16]; uint4 u[2]; } pk;
#pragma unroll
  for (int j = 0; j < 16; j++) pk.o[j] = tile[cc + j][h];
  const int n = mat * 64 + h;
  char* base = Wt_s + (size_t)n * 2048 + (c0 >> 6) * 128;
  const int bc = cc * 2;
  *(uint4*)(base + ((bc) ^ ((n & 7) << 4))) = pk.u[0];
  *(uint4*)(base + ((bc + 16) ^ ((n & 7) << 4))) = pk.u[1];
}

// ---------------------------------------------------------------------------
// Kernel 1: KQV[32768][192] = x * W. 512 blocks x 256 threads, 2 blocks/CU.
// R5 structure (A: coalesced float4 -> regs -> bf16 -> swizzled LDS; W via
// global_load_lds from pre-swizzled Wt_s) PLUS:
//   - 4-deep named A-register pipeline: LOADA(t+2) issued at step t -> one
//     full K-step of latency cover before CVTWRITE consumes it.
//   - counted-vmcnt barrier (T4): GW issued BEFORE LOADA (order pinned by
//     sched_barrier), barrier waits vmcnt(4) lgkmcnt(0) -> the 6 W gloads
//     drain (next MMA needs them), the 4 A-loads FLY ACROSS the barrier.
// ---------------------------------------------------------------------------
__launch_bounds__(256, 2)
__global__ void proj_kernel(const float* __restrict__ x, const char* __restrict__ Wt_s,
                            __bf16* __restrict__ KQV) {
  __shared__ char lds[65536];
  char* A0 = lds;            // [64][128B] bf16 swizzled, 8 KB
  char* A1 = lds + 8192;
  char* W0 = lds + 16384;    // [192][128B] bf16 swizzled, 24 KB
  char* W1 = lds + 40960;

  const int tid = threadIdx.x;
  const int lane = tid & 63;
  const int wave = tid >> 6;  // 0..3
  const int wm = wave >> 1;
  const int wn = wave & 1;
  const int row0 = blockIdx.x * 64;

  // A staging: thread owns row sr, 16 contiguous floats at col sc*16
  const int sr = tid >> 2;
  const int sc = tid & 3;
  const float4* xp = (const float4*)(x + (size_t)(row0 + sr) * 1024 + sc * 16);

  f32x16 acc[3];
#pragma unroll
  for (int i = 0; i < 3; i++) acc[i] = zero16();

  float4 s0[4], s1[4], s2[4], s3[4];

#define SB __builtin_amdgcn_sched_barrier(0)

#define LOADA(rr, t)                                                              \
  {                                                                               \
    _Pragma("unroll") for (int j = 0; j < 4; j++) rr[j] = xp[(t) * 16 + j];       \
  }

#define GW(t, Wbuf)                                                               \
  {                                                                               \
    _Pragma("unroll") for (int j = 0; j < 6; j++) {                               \
      int idx = wave * 64 + j * 256 + lane;                                       \
      GLOAD16(Wt_s + (size_t)(idx >> 3) * 2048 + (t) * 128 + (idx & 7) * 16,      \
              Wbuf + wave * 1024 + j * 4096);                                     \
    }                                                                             \
  }

#define CVTWRITE(rr, Abuf)                                                        \
  {                                                                               \
    union { __bf16 h[16]; uint4 u[2]; } cv;                                       \
    _Pragma("unroll") for (int j = 0; j < 4; j++) {                               \
      cv.h[4 * j + 0] = (__bf16)rr[j].x;                                          \
      cv.h[4 * j + 1] = (__bf16)rr[j].y;                                          \
      cv.h[4 * j + 2] = (__bf16)rr[j].z;                                          \
      cv.h[4 * j + 3] = (__bf16)rr[j].w;                                          \
    }                                                                             \
    *(uint4*)(Abuf + sr * 128 + ((sc * 32) ^ ((sr & 7) << 4))) = cv.u[0];         \
    *(uint4*)(Abuf + sr * 128 + ((sc * 32 + 16) ^ ((sr & 7) << 4))) = cv.u[1];    \
  }

#define MMA(Abuf, Wbuf)                                                           \
  {                                                                               \
    _Pragma("unroll") for (int ks = 0; ks < 4; ks++) {                            \
      int arow = wm * 32 + (lane & 31);                                           \
      int kb = ks * 32 + ((lane >> 5) << 4);                                      \
      v8bf av = *(const v8bf*)(Abuf + arow * 128 + (kb ^ ((arow & 7) << 4)));     \
      _Pragma("unroll") for (int nf = 0; nf < 3; nf++) {                          \
        int brow = wn * 96 + nf * 32 + (lane & 31);                               \
        v8bf bv = *(const v8bf*)(Wbuf + brow * 128 + (kb ^ ((brow & 7) << 4)));   \
        acc[nf] = __builtin_amdgcn_mfma_f32_32x32x16_bf16(av, bv, acc[nf], 0, 0, 0); \
      }                                                                           \
    }                                                                             \
  }

  // counted barriers: vmcnt(4) leaves the 4 newest (LOADA) in flight;
  // lgkmcnt(0) drains ds_writes/reads. BAR0 drains everything (tail).
#define BAR4                                                                      \
  do {                                                                            \
    asm volatile("s_waitcnt vmcnt(4) lgkmcnt(0)" ::: "memory");                   \
    __builtin_amdgcn_s_barrier();                                                 \
    SB;                                                                           \
  } while (0)
#define BAR0                                                                      \
  do {                                                                            \
    asm volatile("s_waitcnt vmcnt(0) lgkmcnt(0)" ::: "memory");                   \
    __builtin_amdgcn_s_barrier();                                                 \
    SB;                                                                           \
  } while (0)

  // STEP(t): GW(t+1) first (so vmcnt(4) drains it), then LOADA(t+2) (flies
  // across the barrier; consumed by CVTWRITE at step t+1).
#define STEP(T, SI, SC_, ACUR, WCUR, ANXT, WNXT)                                  \
  GW(T + 1, WNXT);                                                                \
  SB;                                                                             \
  LOADA(SI, T + 2);                                                               \
  SB;                                                                             \
  MMA(ACUR, WCUR);                                                                \
  CVTWRITE(SC_, ANXT);                                                            \
  BAR4;

  // prologue: stage step 0 (A via regs, W via gload_lds), preload step-1 regs
  GW(0, W0);
  SB;
  LOADA(s0, 0);
  LOADA(s1, 1);
  SB;
  CVTWRITE(s0, A0);
  BAR4;  // drains GW(0)+ds_writes; s1's 4 loads stay in flight

  STEP(0, s2, s1, A0, W0, A1, W1)
  STEP(1, s3, s2, A1, W1, A0, W0)
  STEP(2, s0, s3, A0, W0, A1, W1)
  STEP(3, s1, s0, A1, W1, A0, W0)
  STEP(4, s2, s1, A0, W0, A1, W1)
  STEP(5, s3, s2, A1, W1, A0, W0)
  STEP(6, s0, s3, A0, W0, A1, W1)
  STEP(7, s1, s0, A1, W1, A0, W0)
  STEP(8, s2, s1, A0, W0, A1, W1)
  STEP(9, s3, s2, A1, W1, A0, W0)
  STEP(10, s0, s3, A0, W0, A1, W1)
  STEP(11, s1, s0, A1, W1, A0, W0)
  STEP(12, s2, s1, A0, W0, A1, W1)
  STEP(13, s3, s2, A1, W1, A0, W0)
  // t=14: no LOADA (step 16 doesn't exist); drain everything at the barrier
  GW(15, W1);
  SB;
  MMA(A0, W0);
  CVTWRITE(s3, A1);
  BAR0;
  // t=15
  MMA(A1, W1);

  // epilogue: write bf16 KQV
#pragma unroll
  for (int nf = 0; nf < 3; nf++) {
#pragma unroll
    for (int r = 0; r < 16; r++) {
      int row = row0 + wm * 32 + (r & 3) + ((r >> 2) << 3) + ((lane >> 5) << 2);
      int col = wn * 96 + nf * 32 + (lane & 31);
      KQV[(size_t)row * 192 + col] = (__bf16)acc[nf][r];
    }
  }
#undef STEP
#undef BAR4
#undef BAR0
#undef LOADA
#undef GW
#undef CVTWRITE
#undef MMA
#undef SB
}

// ---------------------------------------------------------------------------
// Kernel 2: causal attention per batch. 256 blocks (= 128 batches x 2 halves)
// x 256 threads (4 waves). Wave owns 32 q-rows. Swapped QK^T -> lane-local
// softmax. (unchanged from R5 — validated)
// ---------------------------------------------------------------------------
__launch_bounds__(256, 1)
__global__ void attn_kernel(const __bf16* __restrict__ KQV, float* __restrict__ out) {
  __shared__ uint4 lds4[81920 / 16];  // K:[256][64] 32KB | Vt:[64][256] 32KB | Q:[128][64] 16KB
  char* Klds = (char*)lds4;
  char* Vlds = (char*)lds4 + 32768;
  char* Qlds = (char*)lds4 + 65536;

  const int tid = threadIdx.x;
  const int lane = tid & 63;
  const int wave = tid >> 6;  // 0..3
  const int b = blockIdx.x >> 1;
  const int half = blockIdx.x & 1;
  const int bt0 = half * 128;
  const size_t base = (size_t)b * 256 * 192;

  {
    int s = tid;
    const uint4* src = (const uint4*)(KQV + base + (size_t)s * 192 + 64);
#pragma unroll
    for (int i = 0; i < 8; i++) {
      uint4 v = src[i];
      int byte = s * 128 + ((i * 16) ^ ((s & 7) << 4));
      *(uint4*)(Klds + byte) = v;
    }
  }
  {
    int s = tid;
    const uint4* src = (const uint4*)(KQV + base + (size_t)s * 192 + 128);
#pragma unroll
    for (int i = 0; i < 8; i++) {
      uint4 v = src[i];
      const ushort* e = (const ushort*)&v;
#pragma unroll
      for (int j = 0; j < 8; j++) {
        int h = i * 8 + j;
        int byte = h * 512 + ((s * 2) ^ ((h & 7) << 4));
        *(ushort*)(Vlds + byte) = e[j];
      }
    }
  }
#pragma unroll
  for (int i = 0; i < 4; i++) {
    int c = tid + i * 256;
    int r = c >> 3, cc = c & 7;
    uint4 v = *(const uint4*)(KQV + base + (size_t)(bt0 + r) * 192 + cc * 8);
    int byte = r * 128 + ((cc * 16) ^ ((r & 7) << 4));
    *(uint4*)(Qlds + byte) = v;
  }
  __syncthreads();

  const int t0 = bt0 + wave * 32;
  const int tg = t0 + (lane & 31);
  const int nf = (t0 >> 5) + 1;

  f32x16 sacc[8];
#pragma unroll
  for (int sf = 0; sf < 8; sf++) {
    f32x16 sv = zero16();
    if (sf < nf) {
#pragma unroll
      for (int ks = 0; ks < 4; ks++) {
        int kbyte = ks * 32 + ((lane >> 5) << 4);
        int krow = sf * 32 + (lane & 31);
        v8bf a = *(const v8bf*)(Klds + krow * 128 + (kbyte ^ ((krow & 7) << 4)));
        int qrow = wave * 32 + (lane & 31);
        v8bf bq = *(const v8bf*)(Qlds + qrow * 128 + (kbyte ^ ((qrow & 7) << 4)));
        sv = __builtin_amdgcn_mfma_f32_32x32x16_bf16(a, bq, sv, 0, 0, 0);
      }
    }
    sacc[sf] = sv;
  }

  float m = -1e30f;
#pragma unroll
  for (int sf = 0; sf < 8; sf++) {
    if (sf < nf) {
#pragma unroll
      for (int r = 0; r < 16; r++) {
        int sg = sf * 32 + (r & 3) + ((r >> 2) << 3) + ((lane >> 5) << 2);
        float v = sacc[sf][r] * 0.125f;
        v = (sg > tg) ? -1e30f : v;
        sacc[sf][r] = v;
        m = fmaxf(m, v);
      }
    }
  }
  m = fmaxf(m, __shfl_xor(m, 32, 64));
  float l = 0.f;
#pragma unroll
  for (int sf = 0; sf < 8; sf++) {
    if (sf < nf) {
#pragma unroll
      for (int r = 0; r < 16; r++) {
        float p = __expf(sacc[sf][r] - m);
        sacc[sf][r] = p;
        l += p;
      }
    }
  }
  l += __shfl_xor(l, 32, 64);
  float inv = 1.0f / l;

  f32x16 oacc[2];
  oacc[0] = zero16();
  oacc[1] = zero16();
  const bool hiLane = (lane >= 32);
#pragma unroll
  for (int sf = 0; sf < 8; sf++) {
    if (sf < nf) {
      uint w[8], ow[8];
#pragma unroll
      for (int q = 0; q < 4; q++) {
        w[2 * q]     = pack_bf16(sacc[sf][4 * q] * inv,     sacc[sf][4 * q + 1] * inv);
        w[2 * q + 1] = pack_bf16(sacc[sf][4 * q + 2] * inv, sacc[sf][4 * q + 3] * inv);
      }
#pragma unroll
      for (int i = 0; i < 8; i++) ow[i] = (uint)__shfl_xor((int)w[i], 32, 64);
#pragma unroll
      for (int ks = 0; ks < 2; ks++) {
        int bse = 4 * ks;
        union { uint u[4]; v8bf v; } A;
        A.u[0] = hiLane ? ow[bse + 2] : w[bse + 0];
        A.u[1] = hiLane ? ow[bse + 3] : w[bse + 1];
        A.u[2] = hiLane ? w[bse + 2] : ow[bse + 0];
        A.u[3] = hiLane ? w[bse + 3] : ow[bse + 1];
        int sbyte0 = (sf * 32 + ks * 16) * 2 + ((lane >> 5) << 4);
#pragma unroll
        for (int hf = 0; hf < 2; hf++) {
          int vrow = hf * 32 + (lane & 31);
          v8bf bv = *(const v8bf*)(Vlds + vrow * 512 + (sbyte0 ^ ((vrow & 7) << 4)));
          oacc[hf] = __builtin_amdgcn_mfma_f32_32x32x16_bf16(A.v, bv, oacc[hf], 0, 0, 0);
        }
      }
    }
  }

#pragma unroll
  for (int hf = 0; hf < 2; hf++) {
#pragma unroll
    for (int r = 0; r < 16; r++) {
      int t = t0 + (r & 3) + ((r >> 2) << 3) + ((lane >> 5) << 2);
      int h = hf * 32 + (lane & 31);
      out[((size_t)b * 256 + t) * 64 + h] = oacc[hf][r];
    }
  }
}

// ---------------------------------------------------------------------------
extern "C" void kernel_launch(void* const* d_in, const int* in_sizes, int n_in,
                              void* d_out, int out_size, void* d_ws, size_t ws_size,
                              hipStream_t stream) {
  const float* x  = (const float*)d_in[0];
  const float* Wk = (const float*)d_in[1];
  const float* Wq = (const float*)d_in[2];
  const float* Wv = (const float*)d_in[3];
  float* out = (float*)d_out;

  // workspace: KQV bf16 [32768][192] (12.58 MB), then pre-swizzled Wt (384 KB)
  __bf16* KQV = (__bf16*)d_ws;
  char* Wt_s  = (char*)d_ws + (size_t)32768 * 192 * 2;

  prep_wt<<<48, 256, 0, stream>>>(Wq, Wk, Wv, Wt_s);
  proj_kernel<<<512, 256, 0, stream>>>(x, Wt_s, KQV);
  attn_kernel<<<256, 256, 0, stream>>>(KQV, out);
}